// Round 9
// baseline (514.339 us; speedup 1.0000x reference)
//
#include <hip/hip_runtime.h>
#include <hip/hip_bf16.h>
#include <math.h>

#define NN 4096
#define CD 768
#define HD 512
#define OD 50
#define FGD 818   // CD + OD

typedef short short8 __attribute__((ext_vector_type(8)));
typedef float f32x4 __attribute__((ext_vector_type(4)));
typedef unsigned short us4 __attribute__((ext_vector_type(4)));
typedef unsigned short ushortT;
typedef unsigned char uchar;

__device__ inline ushortT f2bf(float v) {
    __hip_bfloat16 b = __float2bfloat16(v);
    return *(ushortT*)&b;
}
__device__ inline float bf2f(ushortT u) {
    __hip_bfloat16 b = *(__hip_bfloat16*)&u;
    return __bfloat162float(b);
}

// ---------------------------------------------------------------------------
// K0a: per-label group sums of x columns (fp64).
// ---------------------------------------------------------------------------
__global__ __launch_bounds__(256) void gsum_kernel(const float* __restrict__ x,
                                                   const int* __restrict__ labels,
                                                   double* __restrict__ gsum) {
    int b = blockIdx.x;
    int t = threadIdx.x;
    double a0[3] = {0, 0, 0}, a1[3] = {0, 0, 0};
    for (int rr = 0; rr < 16; ++rr) {
        int row = b * 16 + rr;
        int lab = labels[row];
#pragma unroll
        for (int s = 0; s < 3; ++s) {
            double v = (double)x[(size_t)row * CD + t + s * 256];
            if (lab == 0) a0[s] += v; else a1[s] += v;
        }
    }
#pragma unroll
    for (int s = 0; s < 3; ++s) {
        atomicAdd(&gsum[t + s * 256], a0[s]);
        atomicAdd(&gsum[768 + t + s * 256], a1[s]);
    }
}

// ---------------------------------------------------------------------------
// K0b: threshold scalars. scal[0] = 2*S0.S1, scal[1] = 2*n0*n1.
// ---------------------------------------------------------------------------
__global__ __launch_bounds__(256) void gdot_kernel(const double* __restrict__ gsum,
                                                   const int* __restrict__ labels,
                                                   double* __restrict__ scal) {
    int t = threadIdx.x;
    double d = 0.0;
    for (int c = t; c < CD; c += 256) d += gsum[c] * gsum[768 + c];
    int n0 = 0;
    for (int i = t; i < NN; i += 256) n0 += (labels[i] == 0) ? 1 : 0;
    for (int off = 32; off; off >>= 1) {
        d += __shfl_down(d, off);
        n0 += __shfl_down(n0, off);
    }
    __shared__ double sd[4];
    __shared__ int sn[4];
    int wid = t >> 6, lane = t & 63;
    if (lane == 0) { sd[wid] = d; sn[wid] = n0; }
    __syncthreads();
    if (t == 0) {
        double D = sd[0] + sd[1] + sd[2] + sd[3];
        double N0 = (double)(sn[0] + sn[1] + sn[2] + sn[3]);
        scal[0] = 2.0 * D;
        scal[1] = 2.0 * N0 * ((double)NN - N0);
    }
}

// ---------------------------------------------------------------------------
// K1: FUSED sim+mask, 128x128 tiles. bf16 3-term split MFMA + fp64 recheck
// band (decisions match fp64 path; validated R8). 528 triangular blocks.
// 4 waves; wave -> 64x64 quadrant (4x4 frags of 16x16x32).
// ---------------------------------------------------------------------------
#define BAND 4e-3

__global__ __launch_bounds__(256) void sim_fused(
    const float* __restrict__ x, const ushortT* __restrict__ xh,
    const ushortT* __restrict__ xl, const int* __restrict__ labels,
    const double* __restrict__ scal, ushortT* __restrict__ ab,
    float* __restrict__ lm, int* __restrict__ deg) {
    // triangular mapping over 32 row/col blocks: C(b) = b*(65-b)/2
    int t = blockIdx.x;
    int by = (int)((65.0 - sqrt(4225.0 - 8.0 * (double)t)) * 0.5);
    while (by * (65 - by) / 2 > t) --by;
    while ((by + 1) * (64 - by) / 2 <= t) ++by;
    int bx = by + (t - by * (65 - by) / 2);
    bool diag = (bx == by);

    __shared__ ushortT lds[4 * 128 * 72];   // 73728 B: Ah|Al|Bh|Bl, then flags
    __shared__ int larr[256];
    int tid = threadIdx.x;
    int lane = tid & 63;
    int w = tid >> 6;
    int wr = w >> 1, wc = w & 1;            // 64x64 quadrant
    int m = lane & 15, quad = lane >> 4;
    int row0 = by * 128, col0 = bx * 128;

    if (tid < 128) larr[tid] = labels[row0 + tid];
    else larr[tid] = labels[col0 + tid - 128];

    f32x4 acc[4][4];
#pragma unroll
    for (int i = 0; i < 4; ++i)
#pragma unroll
        for (int j = 0; j < 4; ++j) acc[i][j] = {0.f, 0.f, 0.f, 0.f};

    for (int k0 = 0; k0 < CD; k0 += 64) {
#pragma unroll
        for (int tt = 0; tt < 4; ++tt) {
            int id2 = tid + tt * 256;
            int row = id2 >> 3, c8 = (id2 & 7) * 8;
            *(short8*)&lds[0 * 9216 + row * 72 + c8] =
                *(const short8*)&xh[(size_t)(row0 + row) * CD + k0 + c8];
            *(short8*)&lds[1 * 9216 + row * 72 + c8] =
                *(const short8*)&xl[(size_t)(row0 + row) * CD + k0 + c8];
            *(short8*)&lds[2 * 9216 + row * 72 + c8] =
                *(const short8*)&xh[(size_t)(col0 + row) * CD + k0 + c8];
            *(short8*)&lds[3 * 9216 + row * 72 + c8] =
                *(const short8*)&xl[(size_t)(col0 + row) * CD + k0 + c8];
        }
        __syncthreads();
#pragma unroll
        for (int ks = 0; ks < 2; ++ks) {
            int ko = ks * 32 + quad * 8;
            short8 ah[4], bh[4];
#pragma unroll
            for (int i = 0; i < 4; ++i)
                ah[i] = *(const short8*)&lds[0 * 9216 +
                                             (wr * 64 + i * 16 + m) * 72 + ko];
#pragma unroll
            for (int j = 0; j < 4; ++j)
                bh[j] = *(const short8*)&lds[2 * 9216 +
                                             (wc * 64 + j * 16 + m) * 72 + ko];
#pragma unroll
            for (int i = 0; i < 4; ++i)
#pragma unroll
                for (int j = 0; j < 4; ++j)
                    acc[i][j] = __builtin_amdgcn_mfma_f32_16x16x32_bf16(
                        ah[i], bh[j], acc[i][j], 0, 0, 0);
            short8 al[4];
#pragma unroll
            for (int i = 0; i < 4; ++i)
                al[i] = *(const short8*)&lds[1 * 9216 +
                                             (wr * 64 + i * 16 + m) * 72 + ko];
#pragma unroll
            for (int i = 0; i < 4; ++i)
#pragma unroll
                for (int j = 0; j < 4; ++j)
                    acc[i][j] = __builtin_amdgcn_mfma_f32_16x16x32_bf16(
                        al[i], bh[j], acc[i][j], 0, 0, 0);
            short8 bl[4];
#pragma unroll
            for (int j = 0; j < 4; ++j)
                bl[j] = *(const short8*)&lds[3 * 9216 +
                                             (wc * 64 + j * 16 + m) * 72 + ko];
#pragma unroll
            for (int i = 0; i < 4; ++i)
#pragma unroll
                for (int j = 0; j < 4; ++j)
                    acc[i][j] = __builtin_amdgcn_mfma_f32_16x16x32_bf16(
                        ah[i], bl[j], acc[i][j], 0, 0, 0);
        }
        __syncthreads();
    }

    // ---- edge flags (alias staging LDS) ----
    double thrd;
    {
        double cnt = scal[1];
        thrd = (cnt > 0.0) ? (scal[0] / cnt) : 0.0;
    }
    uchar* flags = (uchar*)lds;             // [128][132]
#pragma unroll
    for (int i = 0; i < 4; ++i)
#pragma unroll
        for (int j = 0; j < 4; ++j) {
#pragma unroll
            for (int r = 0; r < 4; ++r) {
                int row = wr * 64 + i * 16 + quad * 4 + r;
                int col = wc * 64 + j * 16 + m;
                bool same = (larr[row] == larr[128 + col]);
                bool selfp = ((row0 + row) == (col0 + col));
                bool edge = false;
                if (same && !selfp) {
                    double s = (double)acc[i][j][r];
                    if (s <= thrd - BAND) {
                        edge = true;
                    } else if (s <= thrd + BAND) {
                        const float* xi = x + (size_t)(row0 + row) * CD;
                        const float* xj = x + (size_t)(col0 + col) * CD;
                        double e0 = 0.0, e1 = 0.0;
                        for (int k = 0; k < CD; k += 2) {
                            e0 += (double)xi[k] * (double)xj[k];
                            e1 += (double)xi[k + 1] * (double)xj[k + 1];
                        }
                        edge = ((e0 + e1) <= thrd);
                    }
                }
                flags[row * 132 + col] = edge ? 1 : 0;
            }
        }
    __syncthreads();

    // ---- write ab/lm rows for (by,bx) region + row degrees ----
    {
        int r = tid >> 1, q = tid & 1;      // 2 threads per row, 64 cols each
        int cnti = 0;
#pragma unroll
        for (int s = 0; s < 16; ++s) {
            int cb = q * 64 + s * 4;
            float4 f;
            us4 a4;
#pragma unroll
            for (int k2 = 0; k2 < 4; ++k2) {
                int c = cb + k2;
                bool fl = flags[r * 132 + c] != 0;
                cnti += fl ? 1 : 0;
                ((ushortT*)&a4)[k2] =
                    (fl || (diag && r == c)) ? (ushortT)0x3F80 : (ushortT)0;
                ((float*)&f)[k2] = (fl && (row0 + r < col0 + c)) ? 1.0f : 0.0f;
            }
            *(us4*)&ab[(size_t)(row0 + r) * NN + col0 + cb] = a4;
            *(float4*)&lm[(size_t)(row0 + r) * NN + col0 + cb] = f;
        }
        cnti += __shfl_down(cnti, 1);
        if (q == 0 && cnti) atomicAdd(&deg[row0 + r], cnti);
    }

    // ---- mirror region (bx,by) for off-diagonal blocks ----
    if (!diag) {
        int c = tid >> 1, q = tid & 1;
        int cnti = 0;
        float4 fz = {0.0f, 0.0f, 0.0f, 0.0f};
#pragma unroll
        for (int s = 0; s < 16; ++s) {
            int rb = q * 64 + s * 4;
            us4 a4;
#pragma unroll
            for (int k2 = 0; k2 < 4; ++k2) {
                bool fl = flags[(rb + k2) * 132 + c] != 0;
                cnti += fl ? 1 : 0;
                ((ushortT*)&a4)[k2] = fl ? (ushortT)0x3F80 : (ushortT)0;
            }
            *(us4*)&ab[(size_t)(col0 + c) * NN + row0 + rb] = a4;
            *(float4*)&lm[(size_t)(col0 + c) * NN + row0 + rb] = fz;
        }
        cnti += __shfl_down(cnti, 1);
        if (q == 0 && cnti) atomicAdd(&deg[col0 + c], cnti);
    }
}

__global__ void dinv_kernel(const int* __restrict__ deg, float* __restrict__ dinv) {
    int i = blockIdx.x * blockDim.x + threadIdx.x;
    if (i < NN) dinv[i] = (float)(1.0 / sqrt((double)(1 + deg[i])));
}

// ---------------------------------------------------------------------------
// PREP (fused): x -> f_g cols / x-out / xh/xl planes; W1,W2 transposes.
// ---------------------------------------------------------------------------
__global__ __launch_bounds__(256) void prep_kernel(
    const float* __restrict__ x, const float* __restrict__ W1,
    const float* __restrict__ W2, float* __restrict__ fg, float* __restrict__ xo,
    ushortT* __restrict__ xh, ushortT* __restrict__ xl, ushortT* __restrict__ w1t,
    ushortT* __restrict__ w2t) {
    int b = blockIdx.x;
    if (b < 4096) {
        int t = threadIdx.x;
        if (t < 192) {
            float4 v = *(const float4*)&x[(size_t)b * CD + t * 4];
            *(float4*)&xo[(size_t)b * CD + t * 4] = v;
            fg[(size_t)b * FGD + t * 4 + 0] = v.x;
            fg[(size_t)b * FGD + t * 4 + 1] = v.y;
            fg[(size_t)b * FGD + t * 4 + 2] = v.z;
            fg[(size_t)b * FGD + t * 4 + 3] = v.w;
            us4 hh, ll;
            float* vp = (float*)&v;
#pragma unroll
            for (int k = 0; k < 4; ++k) {
                ushortT h = f2bf(vp[k]);
                ((ushortT*)&hh)[k] = h;
                ((ushortT*)&ll)[k] = f2bf(vp[k] - bf2f(h));
            }
            *(us4*)&xh[(size_t)b * CD + t * 4] = hh;
            *(us4*)&xl[(size_t)b * CD + t * 4] = ll;
        }
        return;
    }
    __shared__ float tT[32][33];
    const float* P;
    ushortT* T;
    int K, N, Npad, k0, n0;
    if (b < 4480) {
        int bb = b - 4096;
        P = W1; T = w1t; K = CD; N = HD; Npad = HD;
        k0 = (bb % 24) * 32; n0 = (bb / 24) * 32;
    } else {
        int bb = b - 4480;
        P = W2; T = w2t; K = HD; N = OD; Npad = 64;
        k0 = (bb % 16) * 32; n0 = (bb / 16) * 32;
    }
    int tx = threadIdx.x & 31, ty = threadIdx.x >> 5;
#pragma unroll
    for (int s = 0; s < 4; ++s) {
        int k = k0 + ty + s * 8, n = n0 + tx;
        tT[ty + s * 8][tx] = (k < K && n < N) ? P[(size_t)k * N + n] : 0.0f;
    }
    __syncthreads();
#pragma unroll
    for (int s = 0; s < 4; ++s) {
        int n = n0 + ty + s * 8, k = k0 + tx;
        if (n < Npad && k < K) T[(size_t)n * K + k] = f2bf(tT[tx][ty + s * 8]);
    }
}

// ---------------------------------------------------------------------------
// bf16-MFMA GEMM (verified R6-R8). A row-major MxK; B transposed [Npad][K].
// EPI: 1 = bf16 row-major, 2 = bf16 transposed out.
// ---------------------------------------------------------------------------
template <bool RELU, bool HASBIAS, int EPI>
__global__ __launch_bounds__(256) void gemm_bf16(
    const ushortT* __restrict__ A, const ushortT* __restrict__ B,
    float* __restrict__ C, ushortT* __restrict__ Cb,
    int M, int Nn, int K, int ldc,
    const float* __restrict__ rowscale, const float* __restrict__ bias) {
    __shared__ ushortT lds[2 * 64 * 72];
    int tid = threadIdx.x;
    int lane = tid & 63;
    int w = tid >> 6;
    int wr = w >> 1, wc = w & 1;
    int m = lane & 15, quad = lane >> 4;
    int row0 = blockIdx.y * 64, col0 = blockIdx.x * 64;

    f32x4 acc[2][2] = {{{0.f, 0.f, 0.f, 0.f}, {0.f, 0.f, 0.f, 0.f}},
                       {{0.f, 0.f, 0.f, 0.f}, {0.f, 0.f, 0.f, 0.f}}};

    for (int k0 = 0; k0 < K; k0 += 64) {
#pragma unroll
        for (int t = 0; t < 2; ++t) {
            int id2 = tid + t * 256;
            int row = id2 >> 3, c8 = (id2 & 7) * 8;
            *(short8*)&lds[row * 72 + c8] =
                *(const short8*)&A[(size_t)(row0 + row) * K + k0 + c8];
            *(short8*)&lds[4608 + row * 72 + c8] =
                *(const short8*)&B[(size_t)(col0 + row) * K + k0 + c8];
        }
        __syncthreads();
#pragma unroll
        for (int ks = 0; ks < 2; ++ks) {
            short8 af[2], bf[2];
#pragma unroll
            for (int i = 0; i < 2; ++i)
                af[i] = *(const short8*)&lds[(wr * 32 + i * 16 + m) * 72 +
                                             ks * 32 + quad * 8];
#pragma unroll
            for (int j = 0; j < 2; ++j)
                bf[j] = *(const short8*)&lds[4608 + (wc * 32 + j * 16 + m) * 72 +
                                             ks * 32 + quad * 8];
#pragma unroll
            for (int i = 0; i < 2; ++i)
#pragma unroll
                for (int j = 0; j < 2; ++j)
                    acc[i][j] = __builtin_amdgcn_mfma_f32_16x16x32_bf16(
                        af[i], bf[j], acc[i][j], 0, 0, 0);
        }
        __syncthreads();
    }

    if (EPI == 2) {
        ushortT* Th = lds;
#pragma unroll
        for (int i = 0; i < 2; ++i)
#pragma unroll
            for (int j = 0; j < 2; ++j)
#pragma unroll
                for (int r = 0; r < 4; ++r) {
                    int row = wr * 32 + i * 16 + quad * 4 + r;
                    int col = wc * 32 + j * 16 + m;
                    Th[col * 72 + row] = f2bf(acc[i][j][r] * rowscale[row0 + row]);
                }
        __syncthreads();
#pragma unroll
        for (int t = 0; t < 2; ++t) {
            int id2 = tid + t * 256;
            int cc = id2 >> 3, chunk = id2 & 7;
            *(short8*)&Cb[(size_t)(col0 + cc) * M + row0 + chunk * 8] =
                *(const short8*)&Th[cc * 72 + chunk * 8];
        }
    } else {
#pragma unroll
        for (int i = 0; i < 2; ++i)
#pragma unroll
            for (int j = 0; j < 2; ++j)
#pragma unroll
                for (int r = 0; r < 4; ++r) {
                    int row = wr * 32 + i * 16 + quad * 4 + r;
                    int col = wc * 32 + j * 16 + m;
                    int gr = row0 + row, gc = col0 + col;
                    if (gc < Nn) {
                        float v = acc[i][j][r] * rowscale[gr];
                        if (HASBIAS) v += bias[gc];
                        if (RELU) v = fmaxf(v, 0.0f);
                        Cb[(size_t)gr * ldc + gc] = f2bf(v);
                    }
                }
    }
}

// ---------------------------------------------------------------------------
// Split-K partial GEMM: P[kb][row0..+64][0..64] = A-rows x B-rows over the
// kb-th K chunk. A row-major MxK bf16; B [64][K] bf16. Grid (KS, M/64).
// ---------------------------------------------------------------------------
__global__ __launch_bounds__(256) void gemm_part(
    const ushortT* __restrict__ A, const ushortT* __restrict__ B,
    float* __restrict__ P, int M, int K, int KC) {
    __shared__ ushortT lds[2 * 64 * 72];
    int tid = threadIdx.x;
    int lane = tid & 63;
    int w = tid >> 6;
    int wr = w >> 1, wc = w & 1;
    int m = lane & 15, quad = lane >> 4;
    int kb = blockIdx.x;
    int row0 = blockIdx.y * 64;
    int kbase = kb * KC;

    f32x4 acc[2][2] = {{{0.f, 0.f, 0.f, 0.f}, {0.f, 0.f, 0.f, 0.f}},
                       {{0.f, 0.f, 0.f, 0.f}, {0.f, 0.f, 0.f, 0.f}}};

    for (int k0 = 0; k0 < KC; k0 += 64) {
#pragma unroll
        for (int t = 0; t < 2; ++t) {
            int id2 = tid + t * 256;
            int row = id2 >> 3, c8 = (id2 & 7) * 8;
            *(short8*)&lds[row * 72 + c8] =
                *(const short8*)&A[(size_t)(row0 + row) * K + kbase + k0 + c8];
            *(short8*)&lds[4608 + row * 72 + c8] =
                *(const short8*)&B[(size_t)row * K + kbase + k0 + c8];
        }
        __syncthreads();
#pragma unroll
        for (int ks = 0; ks < 2; ++ks) {
            short8 af[2], bf[2];
#pragma unroll
            for (int i = 0; i < 2; ++i)
                af[i] = *(const short8*)&lds[(wr * 32 + i * 16 + m) * 72 +
                                             ks * 32 + quad * 8];
#pragma unroll
            for (int j = 0; j < 2; ++j)
                bf[j] = *(const short8*)&lds[4608 + (wc * 32 + j * 16 + m) * 72 +
                                             ks * 32 + quad * 8];
#pragma unroll
            for (int i = 0; i < 2; ++i)
#pragma unroll
                for (int j = 0; j < 2; ++j)
                    acc[i][j] = __builtin_amdgcn_mfma_f32_16x16x32_bf16(
                        af[i], bf[j], acc[i][j], 0, 0, 0);
        }
        __syncthreads();
    }
#pragma unroll
    for (int i = 0; i < 2; ++i)
#pragma unroll
        for (int j = 0; j < 2; ++j)
#pragma unroll
            for (int r = 0; r < 4; ++r) {
                int row = wr * 32 + i * 16 + quad * 4 + r;
                int col = wc * 32 + j * 16 + m;
                P[((size_t)kb * M + row0 + row) * 64 + col] = acc[i][j][r];
            }
}

// ---------------------------------------------------------------------------
// k6 epilogue: hw2sT[c][r] = bf16(dinv[r] * sum_kb P6[kb][r][c]); 64 blocks.
// ---------------------------------------------------------------------------
__global__ __launch_bounds__(256) void k6_epi(const float* __restrict__ P6,
                                              const float* __restrict__ dinv,
                                              ushortT* __restrict__ hw2sT) {
    __shared__ ushortT Th[64 * 72];
    int row0 = blockIdx.x * 64;
    int tid = threadIdx.x;
    int rl = tid >> 2, q = tid & 3;
#pragma unroll
    for (int s = 0; s < 16; ++s) {
        int c = q * 16 + s;
        float v = 0.f;
#pragma unroll
        for (int kb = 0; kb < 4; ++kb)
            v += P6[((size_t)kb * NN + row0 + rl) * 64 + c];
        Th[c * 72 + rl] = f2bf(v * dinv[row0 + rl]);
    }
    __syncthreads();
#pragma unroll
    for (int t = 0; t < 2; ++t) {
        int id2 = tid + t * 256;
        int cc = id2 >> 3, chunk = id2 & 7;
        *(short8*)&hw2sT[(size_t)cc * NN + row0 + chunk * 8] =
            *(const short8*)&Th[cc * 72 + chunk * 8];
    }
}

// ---------------------------------------------------------------------------
// k7 epilogue: fg[r][768+c] = dinv[r]*sum_kb P7[kb][r][c] + b2[c], c<50.
// ---------------------------------------------------------------------------
__global__ __launch_bounds__(256) void k7_epi(const float* __restrict__ P7,
                                              const float* __restrict__ dinv,
                                              const float* __restrict__ b2,
                                              float* __restrict__ fg) {
    int row0 = blockIdx.x * 64;
    int tid = threadIdx.x;
    int rl = tid >> 2, q = tid & 3;
    int r = row0 + rl;
    float dv = dinv[r];
#pragma unroll
    for (int s = 0; s < 16; ++s) {
        int c = q * 16 + s;
        if (c < OD) {
            float v = 0.f;
#pragma unroll
            for (int kb = 0; kb < 8; ++kb)
                v += P7[((size_t)kb * NN + r) * 64 + c];
            fg[(size_t)r * FGD + CD + c] = v * dv + b2[c];
        }
    }
}

// ---------------------------------------------------------------------------
// out[i] = f_g[i,:] . fcW + fcb
// ---------------------------------------------------------------------------
__global__ __launch_bounds__(256) void out_kernel(const float* __restrict__ fg,
                                                  const float* __restrict__ fcW,
                                                  const float* __restrict__ fcb,
                                                  float* __restrict__ out) {
    int i = blockIdx.x;
    float s = 0.0f;
    for (int j = threadIdx.x; j < FGD; j += 256)
        s += fg[(size_t)i * FGD + j] * fcW[j];
    for (int off = 32; off; off >>= 1) s += __shfl_down(s, off);
    __shared__ float sw[4];
    int wid = threadIdx.x >> 6, lane = threadIdx.x & 63;
    if (lane == 0) sw[wid] = s;
    __syncthreads();
    if (threadIdx.x == 0) out[i] = sw[0] + sw[1] + sw[2] + sw[3] + fcb[0];
}

extern "C" void kernel_launch(void* const* d_in, const int* in_sizes, int n_in,
                              void* d_out, int out_size, void* d_ws, size_t ws_size,
                              hipStream_t stream) {
    const float* x = (const float*)d_in[0];
    const int* labels = (const int*)d_in[1];
    const float* W1 = (const float*)d_in[2];
    const float* b1 = (const float*)d_in[3];
    const float* W2 = (const float*)d_in[4];
    const float* b2 = (const float*)d_in[5];
    const float* fcW = (const float*)d_in[6];
    const float* fcb = (const float*)d_in[7];
    float* outp = (float*)d_out;

    const size_t o_out = 0;
    const size_t o_fg = 4096;
    const size_t o_lm = o_fg + (size_t)NN * FGD;
    const size_t o_x = o_lm + (size_t)NN * NN;

    // workspace layout
    char* ws = (char*)d_ws;
    size_t off = 0;
    ushortT* ab = (ushortT*)(ws + off); off += (size_t)NN * NN * 2;     // 32 MiB
    ushortT* xh = (ushortT*)(ws + off); off += (size_t)NN * CD * 2;
    ushortT* xl = (ushortT*)(ws + off); off += (size_t)NN * CD * 2;
    ushortT* w1t = (ushortT*)(ws + off); off += (size_t)HD * CD * 2;
    ushortT* xw1sT = (ushortT*)(ws + off); off += (size_t)HD * NN * 2;
    ushortT* hb = (ushortT*)(ws + off); off += (size_t)NN * HD * 2;
    ushortT* w2t = (ushortT*)(ws + off); off += (size_t)64 * HD * 2;
    ushortT* hw2sT = (ushortT*)(ws + off); off += (size_t)64 * NN * 2;
    float* P6 = (float*)(ws + off); off += (size_t)4 * NN * 64 * 4;     // 4 MiB
    float* P7 = (float*)(ws + off); off += (size_t)8 * NN * 64 * 4;     // 8 MiB
    float* dinv = (float*)(ws + off); off += (size_t)NN * 4;
    char* zbase = ws + off;
    int* deg = (int*)(ws + off); off += (size_t)NN * 4;
    double* gsum = (double*)(ws + off); off += 1536 * 8;
    double* scal = (double*)(ws + off); off += 16;
    size_t zbytes = (size_t)NN * 4 + 1536 * 8 + 16;

    hipMemsetAsync(zbase, 0, zbytes, stream);

    // prep: x copies/casts (hi+lo planes) + weight transposes
    prep_kernel<<<4512, 256, 0, stream>>>(x, W1, W2, outp + o_fg, outp + o_x, xh, xl,
                                          w1t, w2t);

    // threshold via group sums (exact fp64)
    gsum_kernel<<<256, 256, 0, stream>>>(x, labels, gsum);
    gdot_kernel<<<1, 256, 0, stream>>>(gsum, labels, scal);

    // fused sim(bf16-split + fp64 recheck) + mask + adjacency + degrees
    sim_fused<<<528, 256, 0, stream>>>(x, xh, xl, labels, scal, ab, outp + o_lm, deg);

    dinv_kernel<<<(NN + 255) / 256, 256, 0, stream>>>(deg, dinv);

    // K4: xw1sT = (dinv ⊙ (x @ W1))^T   [M=4096,N=512,K=768]
    gemm_bf16<false, false, 2><<<dim3(HD / 64, NN / 64), 256, 0, stream>>>(
        xh, w1t, nullptr, xw1sT, NN, HD, CD, 0, dinv, nullptr);

    // K5: h = relu(dinv ⊙ (a @ xw1s) + b1), bf16 row-major  [K=4096]
    gemm_bf16<true, true, 1><<<dim3(HD / 64, NN / 64), 256, 0, stream>>>(
        ab, xw1sT, nullptr, hb, NN, HD, NN, HD, dinv, b1);

    // K6: hw2sT via split-K partials + epilogue
    gemm_part<<<dim3(4, NN / 64), 256, 0, stream>>>(hb, w2t, P6, NN, HD, HD / 4);
    k6_epi<<<NN / 64, 256, 0, stream>>>(P6, dinv, hw2sT);

    // K7: g via split-K partials + epilogue -> f_g[:, 768:818]
    gemm_part<<<dim3(8, NN / 64), 256, 0, stream>>>(ab, hw2sT, P7, NN, NN, NN / 8);
    k7_epi<<<NN / 64, 256, 0, stream>>>(P7, dinv, b2, outp + o_fg);

    out_kernel<<<NN, 256, 0, stream>>>(outp + o_fg, fcW, fcb, outp + o_out);
}

// Round 10
// 432.700 us; speedup vs baseline: 1.1887x; 1.1887x over previous
//
#include <hip/hip_runtime.h>
#include <hip/hip_bf16.h>
#include <math.h>

#define NN 4096
#define CD 768
#define HD 512
#define OD 50
#define FGD 818   // CD + OD

typedef short short8 __attribute__((ext_vector_type(8)));
typedef float f32x4 __attribute__((ext_vector_type(4)));
typedef unsigned short us4 __attribute__((ext_vector_type(4)));
typedef unsigned short ushortT;
typedef unsigned char uchar;

__device__ inline ushortT f2bf(float v) {
    __hip_bfloat16 b = __float2bfloat16(v);
    return *(ushortT*)&b;
}
__device__ inline float bf2f(ushortT u) {
    __hip_bfloat16 b = *(__hip_bfloat16*)&u;
    return __bfloat162float(b);
}
__device__ inline float dinv_of(int d) {
    return (float)(1.0 / sqrt((double)(1 + d)));
}

// ---------------------------------------------------------------------------
// K0a: per-label group sums of x columns (fp64).
// ---------------------------------------------------------------------------
__global__ __launch_bounds__(256) void gsum_kernel(const float* __restrict__ x,
                                                   const int* __restrict__ labels,
                                                   double* __restrict__ gsum) {
    int b = blockIdx.x;
    int t = threadIdx.x;
    double a0[3] = {0, 0, 0}, a1[3] = {0, 0, 0};
    for (int rr = 0; rr < 16; ++rr) {
        int row = b * 16 + rr;
        int lab = labels[row];
#pragma unroll
        for (int s = 0; s < 3; ++s) {
            double v = (double)x[(size_t)row * CD + t + s * 256];
            if (lab == 0) a0[s] += v; else a1[s] += v;
        }
    }
#pragma unroll
    for (int s = 0; s < 3; ++s) {
        atomicAdd(&gsum[t + s * 256], a0[s]);
        atomicAdd(&gsum[768 + t + s * 256], a1[s]);
    }
}

// ---------------------------------------------------------------------------
// K0b: threshold scalars. scal[0] = 2*S0.S1, scal[1] = 2*n0*n1.
// ---------------------------------------------------------------------------
__global__ __launch_bounds__(256) void gdot_kernel(const double* __restrict__ gsum,
                                                   const int* __restrict__ labels,
                                                   double* __restrict__ scal) {
    int t = threadIdx.x;
    double d = 0.0;
    for (int c = t; c < CD; c += 256) d += gsum[c] * gsum[768 + c];
    int n0 = 0;
    for (int i = t; i < NN; i += 256) n0 += (labels[i] == 0) ? 1 : 0;
    for (int off = 32; off; off >>= 1) {
        d += __shfl_down(d, off);
        n0 += __shfl_down(n0, off);
    }
    __shared__ double sd[4];
    __shared__ int sn[4];
    int wid = t >> 6, lane = t & 63;
    if (lane == 0) { sd[wid] = d; sn[wid] = n0; }
    __syncthreads();
    if (t == 0) {
        double D = sd[0] + sd[1] + sd[2] + sd[3];
        double N0 = (double)(sn[0] + sn[1] + sn[2] + sn[3]);
        scal[0] = 2.0 * D;
        scal[1] = 2.0 * N0 * ((double)NN - N0);
    }
}

// ---------------------------------------------------------------------------
// K1: FUSED sim+mask (R8 config — 64x64 tiles, 2080 triangular blocks;
// bf16 3-term split MFMA + fp64 recheck band; verified + fastest at 127 us).
// ---------------------------------------------------------------------------
#define BAND 4e-3

__global__ __launch_bounds__(256) void sim_fused(
    const float* __restrict__ x, const ushortT* __restrict__ xh,
    const ushortT* __restrict__ xl, const int* __restrict__ labels,
    const double* __restrict__ scal, ushortT* __restrict__ ab,
    float* __restrict__ lm, int* __restrict__ deg) {
    // triangular mapping: t -> (by, bx), bx >= by
    int t = blockIdx.x;
    int by = (int)((129.0 - sqrt(16641.0 - 8.0 * (double)t)) * 0.5);
    while (by * (129 - by) / 2 > t) --by;
    while ((by + 1) * (129 - (by + 1)) / 2 <= t) ++by;
    int bx = by + (t - by * (129 - by) / 2);
    bool diag = (bx == by);

    __shared__ ushortT lds[4 * 64 * 72];    // 36864 B: Rh|Rl|Ch|Cl, then flags
    __shared__ int larr[128];
    int tid = threadIdx.x;
    int lane = tid & 63;
    int w = tid >> 6;
    int wr = w >> 1, wc = w & 1;
    int m = lane & 15, quad = lane >> 4;
    int row0 = by * 64, col0 = bx * 64;

    if (tid < 64) larr[tid] = labels[row0 + tid];
    else if (tid < 128) larr[tid] = labels[col0 + tid - 64];

    f32x4 acc[2][2] = {{{0.f, 0.f, 0.f, 0.f}, {0.f, 0.f, 0.f, 0.f}},
                       {{0.f, 0.f, 0.f, 0.f}, {0.f, 0.f, 0.f, 0.f}}};

    for (int k0 = 0; k0 < CD; k0 += 64) {
#pragma unroll
        for (int tt = 0; tt < 2; ++tt) {
            int id2 = tid + tt * 256;
            int row = id2 >> 3, c8 = (id2 & 7) * 8;
            *(short8*)&lds[0 * 4608 + row * 72 + c8] =
                *(const short8*)&xh[(size_t)(row0 + row) * CD + k0 + c8];
            *(short8*)&lds[1 * 4608 + row * 72 + c8] =
                *(const short8*)&xl[(size_t)(row0 + row) * CD + k0 + c8];
            *(short8*)&lds[2 * 4608 + row * 72 + c8] =
                *(const short8*)&xh[(size_t)(col0 + row) * CD + k0 + c8];
            *(short8*)&lds[3 * 4608 + row * 72 + c8] =
                *(const short8*)&xl[(size_t)(col0 + row) * CD + k0 + c8];
        }
        __syncthreads();
#pragma unroll
        for (int ks = 0; ks < 2; ++ks) {
            short8 ah[2], al[2], bh[2], bl[2];
#pragma unroll
            for (int i = 0; i < 2; ++i) {
                int ro = (wr * 32 + i * 16 + m) * 72 + ks * 32 + quad * 8;
                ah[i] = *(const short8*)&lds[0 * 4608 + ro];
                al[i] = *(const short8*)&lds[1 * 4608 + ro];
            }
#pragma unroll
            for (int j = 0; j < 2; ++j) {
                int co = (wc * 32 + j * 16 + m) * 72 + ks * 32 + quad * 8;
                bh[j] = *(const short8*)&lds[2 * 4608 + co];
                bl[j] = *(const short8*)&lds[3 * 4608 + co];
            }
#pragma unroll
            for (int i = 0; i < 2; ++i)
#pragma unroll
                for (int j = 0; j < 2; ++j) {
                    acc[i][j] = __builtin_amdgcn_mfma_f32_16x16x32_bf16(
                        ah[i], bh[j], acc[i][j], 0, 0, 0);
                    acc[i][j] = __builtin_amdgcn_mfma_f32_16x16x32_bf16(
                        ah[i], bl[j], acc[i][j], 0, 0, 0);
                    acc[i][j] = __builtin_amdgcn_mfma_f32_16x16x32_bf16(
                        al[i], bh[j], acc[i][j], 0, 0, 0);
                }
        }
        __syncthreads();
    }

    // ---- edge flags (alias staging LDS) ----
    double thrd;
    {
        double cnt = scal[1];
        thrd = (cnt > 0.0) ? (scal[0] / cnt) : 0.0;
    }
    uchar* flags = (uchar*)lds;             // [64][68]
#pragma unroll
    for (int i = 0; i < 2; ++i)
#pragma unroll
        for (int j = 0; j < 2; ++j) {
#pragma unroll
            for (int r = 0; r < 4; ++r) {
                int row = wr * 32 + i * 16 + quad * 4 + r;
                int col = wc * 32 + j * 16 + m;
                bool same = (larr[row] == larr[64 + col]);
                bool selfp = ((row0 + row) == (col0 + col));
                bool edge = false;
                if (same && !selfp) {
                    double s = (double)acc[i][j][r];
                    if (s <= thrd - BAND) {
                        edge = true;
                    } else if (s <= thrd + BAND) {
                        const float* xi = x + (size_t)(row0 + row) * CD;
                        const float* xj = x + (size_t)(col0 + col) * CD;
                        double e0 = 0.0, e1 = 0.0;
                        for (int k = 0; k < CD; k += 2) {
                            e0 += (double)xi[k] * (double)xj[k];
                            e1 += (double)xi[k + 1] * (double)xj[k + 1];
                        }
                        edge = ((e0 + e1) <= thrd);
                    }
                }
                flags[row * 68 + col] = edge ? 1 : 0;
            }
        }
    __syncthreads();

    // ---- write ab/lm rows for (by,bx) region + row degrees ----
    {
        int r = tid >> 2, q = tid & 3;
        int cnti = 0;
#pragma unroll
        for (int s = 0; s < 4; ++s) {
            int cb = q * 16 + s * 4;
            float4 f;
            us4 a4;
#pragma unroll
            for (int k2 = 0; k2 < 4; ++k2) {
                int c = cb + k2;
                bool fl = flags[r * 68 + c] != 0;
                cnti += fl ? 1 : 0;
                ((ushortT*)&a4)[k2] =
                    (fl || (diag && r == c)) ? (ushortT)0x3F80 : (ushortT)0;
                ((float*)&f)[k2] = (fl && (row0 + r < col0 + c)) ? 1.0f : 0.0f;
            }
            *(us4*)&ab[(size_t)(row0 + r) * NN + col0 + cb] = a4;
            *(float4*)&lm[(size_t)(row0 + r) * NN + col0 + cb] = f;
        }
        cnti += __shfl_down(cnti, 1);
        cnti += __shfl_down(cnti, 2);
        if (q == 0 && cnti) atomicAdd(&deg[row0 + r], cnti);
    }

    // ---- mirror region (bx,by) for off-diagonal blocks ----
    if (!diag) {
        int c = tid >> 2, q = tid & 3;
        int cnti = 0;
        float4 fz = {0.0f, 0.0f, 0.0f, 0.0f};
#pragma unroll
        for (int s = 0; s < 4; ++s) {
            int rb = q * 16 + s * 4;
            us4 a4;
#pragma unroll
            for (int k2 = 0; k2 < 4; ++k2) {
                bool fl = flags[(rb + k2) * 68 + c] != 0;
                cnti += fl ? 1 : 0;
                ((ushortT*)&a4)[k2] = fl ? (ushortT)0x3F80 : (ushortT)0;
            }
            *(us4*)&ab[(size_t)(col0 + c) * NN + row0 + rb] = a4;
            *(float4*)&lm[(size_t)(col0 + c) * NN + row0 + rb] = fz;
        }
        cnti += __shfl_down(cnti, 1);
        cnti += __shfl_down(cnti, 2);
        if (q == 0 && cnti) atomicAdd(&deg[col0 + c], cnti);
    }
}

// ---------------------------------------------------------------------------
// PREP (fused): x -> f_g cols / x-out / xh/xl planes; W1,W2 transposes.
// ---------------------------------------------------------------------------
__global__ __launch_bounds__(256) void prep_kernel(
    const float* __restrict__ x, const float* __restrict__ W1,
    const float* __restrict__ W2, float* __restrict__ fg, float* __restrict__ xo,
    ushortT* __restrict__ xh, ushortT* __restrict__ xl, ushortT* __restrict__ w1t,
    ushortT* __restrict__ w2t) {
    int b = blockIdx.x;
    if (b < 4096) {
        int t = threadIdx.x;
        if (t < 192) {
            float4 v = *(const float4*)&x[(size_t)b * CD + t * 4];
            *(float4*)&xo[(size_t)b * CD + t * 4] = v;
            fg[(size_t)b * FGD + t * 4 + 0] = v.x;
            fg[(size_t)b * FGD + t * 4 + 1] = v.y;
            fg[(size_t)b * FGD + t * 4 + 2] = v.z;
            fg[(size_t)b * FGD + t * 4 + 3] = v.w;
            us4 hh, ll;
            float* vp = (float*)&v;
#pragma unroll
            for (int k = 0; k < 4; ++k) {
                ushortT h = f2bf(vp[k]);
                ((ushortT*)&hh)[k] = h;
                ((ushortT*)&ll)[k] = f2bf(vp[k] - bf2f(h));
            }
            *(us4*)&xh[(size_t)b * CD + t * 4] = hh;
            *(us4*)&xl[(size_t)b * CD + t * 4] = ll;
        }
        return;
    }
    __shared__ float tT[32][33];
    const float* P;
    ushortT* T;
    int K, N, Npad, k0, n0;
    if (b < 4480) {
        int bb = b - 4096;
        P = W1; T = w1t; K = CD; N = HD; Npad = HD;
        k0 = (bb % 24) * 32; n0 = (bb / 24) * 32;
    } else {
        int bb = b - 4480;
        P = W2; T = w2t; K = HD; N = OD; Npad = 64;
        k0 = (bb % 16) * 32; n0 = (bb / 16) * 32;
    }
    int tx = threadIdx.x & 31, ty = threadIdx.x >> 5;
#pragma unroll
    for (int s = 0; s < 4; ++s) {
        int k = k0 + ty + s * 8, n = n0 + tx;
        tT[ty + s * 8][tx] = (k < K && n < N) ? P[(size_t)k * N + n] : 0.0f;
    }
    __syncthreads();
#pragma unroll
    for (int s = 0; s < 4; ++s) {
        int n = n0 + ty + s * 8, k = k0 + tx;
        if (n < Npad && k < K) T[(size_t)n * K + k] = f2bf(tT[tx][ty + s * 8]);
    }
}

// ---------------------------------------------------------------------------
// bf16-MFMA GEMM (verified R6-R9). A row-major MxK; B transposed [Npad][K].
// rowscale computed inline from deg. EPI: 1 = bf16 row-major, 2 = bf16
// transposed out.
// ---------------------------------------------------------------------------
template <bool RELU, bool HASBIAS, int EPI>
__global__ __launch_bounds__(256) void gemm_bf16(
    const ushortT* __restrict__ A, const ushortT* __restrict__ B,
    ushortT* __restrict__ Cb, int M, int Nn, int K, int ldc,
    const int* __restrict__ deg, const float* __restrict__ bias) {
    __shared__ ushortT lds[2 * 64 * 72];
    int tid = threadIdx.x;
    int lane = tid & 63;
    int w = tid >> 6;
    int wr = w >> 1, wc = w & 1;
    int m = lane & 15, quad = lane >> 4;
    int row0 = blockIdx.y * 64, col0 = blockIdx.x * 64;

    f32x4 acc[2][2] = {{{0.f, 0.f, 0.f, 0.f}, {0.f, 0.f, 0.f, 0.f}},
                       {{0.f, 0.f, 0.f, 0.f}, {0.f, 0.f, 0.f, 0.f}}};

    for (int k0 = 0; k0 < K; k0 += 64) {
#pragma unroll
        for (int t = 0; t < 2; ++t) {
            int id2 = tid + t * 256;
            int row = id2 >> 3, c8 = (id2 & 7) * 8;
            *(short8*)&lds[row * 72 + c8] =
                *(const short8*)&A[(size_t)(row0 + row) * K + k0 + c8];
            *(short8*)&lds[4608 + row * 72 + c8] =
                *(const short8*)&B[(size_t)(col0 + row) * K + k0 + c8];
        }
        __syncthreads();
#pragma unroll
        for (int ks = 0; ks < 2; ++ks) {
            short8 af[2], bf[2];
#pragma unroll
            for (int i = 0; i < 2; ++i)
                af[i] = *(const short8*)&lds[(wr * 32 + i * 16 + m) * 72 +
                                             ks * 32 + quad * 8];
#pragma unroll
            for (int j = 0; j < 2; ++j)
                bf[j] = *(const short8*)&lds[4608 + (wc * 32 + j * 16 + m) * 72 +
                                             ks * 32 + quad * 8];
#pragma unroll
            for (int i = 0; i < 2; ++i)
#pragma unroll
                for (int j = 0; j < 2; ++j)
                    acc[i][j] = __builtin_amdgcn_mfma_f32_16x16x32_bf16(
                        af[i], bf[j], acc[i][j], 0, 0, 0);
        }
        __syncthreads();
    }

    if (EPI == 2) {
        ushortT* Th = lds;
#pragma unroll
        for (int i = 0; i < 2; ++i)
#pragma unroll
            for (int j = 0; j < 2; ++j)
#pragma unroll
                for (int r = 0; r < 4; ++r) {
                    int row = wr * 32 + i * 16 + quad * 4 + r;
                    int col = wc * 32 + j * 16 + m;
                    float dv = dinv_of(deg[row0 + row]);
                    Th[col * 72 + row] = f2bf(acc[i][j][r] * dv);
                }
        __syncthreads();
#pragma unroll
        for (int t = 0; t < 2; ++t) {
            int id2 = tid + t * 256;
            int cc = id2 >> 3, chunk = id2 & 7;
            *(short8*)&Cb[(size_t)(col0 + cc) * M + row0 + chunk * 8] =
                *(const short8*)&Th[cc * 72 + chunk * 8];
        }
    } else {
#pragma unroll
        for (int i = 0; i < 2; ++i)
#pragma unroll
            for (int j = 0; j < 2; ++j)
#pragma unroll
                for (int r = 0; r < 4; ++r) {
                    int row = wr * 32 + i * 16 + quad * 4 + r;
                    int col = wc * 32 + j * 16 + m;
                    int gr = row0 + row, gc = col0 + col;
                    if (gc < Nn) {
                        float v = acc[i][j][r] * dinv_of(deg[gr]);
                        if (HASBIAS) v += bias[gc];
                        if (RELU) v = fmaxf(v, 0.0f);
                        Cb[(size_t)gr * ldc + gc] = f2bf(v);
                    }
                }
    }
}

// ---------------------------------------------------------------------------
// Split-K partial GEMM: P[kb][row0..+64][0..64]; grid (KS, M/64).
// ---------------------------------------------------------------------------
__global__ __launch_bounds__(256) void gemm_part(
    const ushortT* __restrict__ A, const ushortT* __restrict__ B,
    float* __restrict__ P, int M, int K, int KC) {
    __shared__ ushortT lds[2 * 64 * 72];
    int tid = threadIdx.x;
    int lane = tid & 63;
    int w = tid >> 6;
    int wr = w >> 1, wc = w & 1;
    int m = lane & 15, quad = lane >> 4;
    int kb = blockIdx.x;
    int row0 = blockIdx.y * 64;
    int kbase = kb * KC;

    f32x4 acc[2][2] = {{{0.f, 0.f, 0.f, 0.f}, {0.f, 0.f, 0.f, 0.f}},
                       {{0.f, 0.f, 0.f, 0.f}, {0.f, 0.f, 0.f, 0.f}}};

    for (int k0 = 0; k0 < KC; k0 += 64) {
#pragma unroll
        for (int t = 0; t < 2; ++t) {
            int id2 = tid + t * 256;
            int row = id2 >> 3, c8 = (id2 & 7) * 8;
            *(short8*)&lds[row * 72 + c8] =
                *(const short8*)&A[(size_t)(row0 + row) * K + kbase + k0 + c8];
            *(short8*)&lds[4608 + row * 72 + c8] =
                *(const short8*)&B[(size_t)row * K + kbase + k0 + c8];
        }
        __syncthreads();
#pragma unroll
        for (int ks = 0; ks < 2; ++ks) {
            short8 af[2], bf[2];
#pragma unroll
            for (int i = 0; i < 2; ++i)
                af[i] = *(const short8*)&lds[(wr * 32 + i * 16 + m) * 72 +
                                             ks * 32 + quad * 8];
#pragma unroll
            for (int j = 0; j < 2; ++j)
                bf[j] = *(const short8*)&lds[4608 + (wc * 32 + j * 16 + m) * 72 +
                                             ks * 32 + quad * 8];
#pragma unroll
            for (int i = 0; i < 2; ++i)
#pragma unroll
                for (int j = 0; j < 2; ++j)
                    acc[i][j] = __builtin_amdgcn_mfma_f32_16x16x32_bf16(
                        af[i], bf[j], acc[i][j], 0, 0, 0);
        }
        __syncthreads();
    }
#pragma unroll
    for (int i = 0; i < 2; ++i)
#pragma unroll
        for (int j = 0; j < 2; ++j)
#pragma unroll
            for (int r = 0; r < 4; ++r) {
                int row = wr * 32 + i * 16 + quad * 4 + r;
                int col = wc * 32 + j * 16 + m;
                P[((size_t)kb * M + row0 + row) * 64 + col] = acc[i][j][r];
            }
}

// ---------------------------------------------------------------------------
// k6 epilogue: hw2sT[c][r] = bf16(dinv[r] * sum_kb P6[kb][r][c]); 64 blocks.
// ---------------------------------------------------------------------------
__global__ __launch_bounds__(256) void k6_epi(const float* __restrict__ P6,
                                              const int* __restrict__ deg,
                                              ushortT* __restrict__ hw2sT) {
    __shared__ ushortT Th[64 * 72];
    int row0 = blockIdx.x * 64;
    int tid = threadIdx.x;
    int rl = tid >> 2, q = tid & 3;
    float dv = dinv_of(deg[row0 + rl]);
#pragma unroll
    for (int s = 0; s < 16; ++s) {
        int c = q * 16 + s;
        float v = 0.f;
#pragma unroll
        for (int kb = 0; kb < 4; ++kb)
            v += P6[((size_t)kb * NN + row0 + rl) * 64 + c];
        Th[c * 72 + rl] = f2bf(v * dv);
    }
    __syncthreads();
#pragma unroll
    for (int t = 0; t < 2; ++t) {
        int id2 = tid + t * 256;
        int cc = id2 >> 3, chunk = id2 & 7;
        *(short8*)&hw2sT[(size_t)cc * NN + row0 + chunk * 8] =
            *(const short8*)&Th[cc * 72 + chunk * 8];
    }
}

// ---------------------------------------------------------------------------
// k7 epilogue + final fc: writes g into f_g AND computes out[r] =
// f_g[r,:].fcW + fcb (g part from registers, x part re-read from f_g).
// 64 blocks x 256 threads; 4 threads per row.
// ---------------------------------------------------------------------------
__global__ __launch_bounds__(256) void k7_epi_out(
    const float* __restrict__ P7, const int* __restrict__ deg,
    const float* __restrict__ b2, const float* __restrict__ fcW,
    const float* __restrict__ fcb, float* __restrict__ fg,
    float* __restrict__ out) {
    int row0 = blockIdx.x * 64;
    int tid = threadIdx.x;
    int rl = tid >> 2, q = tid & 3;
    int r = row0 + rl;
    float dv = dinv_of(deg[r]);
    float sg = 0.f;
#pragma unroll
    for (int s = 0; s < 16; ++s) {
        int c = q * 16 + s;
        if (c < OD) {
            float v = 0.f;
#pragma unroll
            for (int kb = 0; kb < 8; ++kb)
                v += P7[((size_t)kb * NN + r) * 64 + c];
            v = v * dv + b2[c];
            fg[(size_t)r * FGD + CD + c] = v;
            sg += v * fcW[CD + c];
        }
    }
    // x-part dot (f_g rows are 8B-aligned: use float2)
    const float* fr = fg + (size_t)r * FGD;
    float sx = 0.f;
    for (int k = q * 192; k < (q + 1) * 192; k += 2) {
        float2 vv = *(const float2*)&fr[k];
        float2 ww = *(const float2*)&fcW[k];
        sx += vv.x * ww.x + vv.y * ww.y;
    }
    float s = sx + sg;
    s += __shfl_down(s, 1);
    s += __shfl_down(s, 2);
    if (q == 0) out[r] = s + fcb[0];
}

extern "C" void kernel_launch(void* const* d_in, const int* in_sizes, int n_in,
                              void* d_out, int out_size, void* d_ws, size_t ws_size,
                              hipStream_t stream) {
    const float* x = (const float*)d_in[0];
    const int* labels = (const int*)d_in[1];
    const float* W1 = (const float*)d_in[2];
    const float* b1 = (const float*)d_in[3];
    const float* W2 = (const float*)d_in[4];
    const float* b2 = (const float*)d_in[5];
    const float* fcW = (const float*)d_in[6];
    const float* fcb = (const float*)d_in[7];
    float* outp = (float*)d_out;

    const size_t o_out = 0;
    const size_t o_fg = 4096;
    const size_t o_lm = o_fg + (size_t)NN * FGD;
    const size_t o_x = o_lm + (size_t)NN * NN;

    // workspace layout
    char* ws = (char*)d_ws;
    size_t off = 0;
    ushortT* ab = (ushortT*)(ws + off); off += (size_t)NN * NN * 2;     // 32 MiB
    ushortT* xh = (ushortT*)(ws + off); off += (size_t)NN * CD * 2;
    ushortT* xl = (ushortT*)(ws + off); off += (size_t)NN * CD * 2;
    ushortT* w1t = (ushortT*)(ws + off); off += (size_t)HD * CD * 2;
    ushortT* xw1sT = (ushortT*)(ws + off); off += (size_t)HD * NN * 2;
    ushortT* hb = (ushortT*)(ws + off); off += (size_t)NN * HD * 2;
    ushortT* w2t = (ushortT*)(ws + off); off += (size_t)64 * HD * 2;
    ushortT* hw2sT = (ushortT*)(ws + off); off += (size_t)64 * NN * 2;
    float* P6 = (float*)(ws + off); off += (size_t)4 * NN * 64 * 4;     // 4 MiB
    float* P7 = (float*)(ws + off); off += (size_t)8 * NN * 64 * 4;     // 8 MiB
    char* zbase = ws + off;
    int* deg = (int*)(ws + off); off += (size_t)NN * 4;
    double* gsum = (double*)(ws + off); off += 1536 * 8;
    double* scal = (double*)(ws + off); off += 16;
    size_t zbytes = (size_t)NN * 4 + 1536 * 8 + 16;

    hipMemsetAsync(zbase, 0, zbytes, stream);

    // prep: x copies/casts (hi+lo planes) + weight transposes
    prep_kernel<<<4512, 256, 0, stream>>>(x, W1, W2, outp + o_fg, outp + o_x, xh, xl,
                                          w1t, w2t);

    // threshold via group sums (exact fp64)
    gsum_kernel<<<256, 256, 0, stream>>>(x, labels, gsum);
    gdot_kernel<<<1, 256, 0, stream>>>(gsum, labels, scal);

    // fused sim(bf16-split + fp64 recheck) + mask + adjacency + degrees
    sim_fused<<<2080, 256, 0, stream>>>(x, xh, xl, labels, scal, ab, outp + o_lm, deg);

    // K4: xw1sT = (dinv ⊙ (x @ W1))^T   [M=4096,N=512,K=768]
    gemm_bf16<false, false, 2><<<dim3(HD / 64, NN / 64), 256, 0, stream>>>(
        xh, w1t, xw1sT, NN, HD, CD, 0, deg, nullptr);

    // K5: h = relu(dinv ⊙ (a @ xw1s) + b1), bf16 row-major  [K=4096]
    gemm_bf16<true, true, 1><<<dim3(HD / 64, NN / 64), 256, 0, stream>>>(
        ab, xw1sT, hb, NN, HD, NN, HD, deg, b1);

    // K6: hw2sT via split-K partials + epilogue
    gemm_part<<<dim3(4, NN / 64), 256, 0, stream>>>(hb, w2t, P6, NN, HD, HD / 4);
    k6_epi<<<NN / 64, 256, 0, stream>>>(P6, deg, hw2sT);

    // K7: g via split-K partials + fused epilogue/out
    gemm_part<<<dim3(8, NN / 64), 256, 0, stream>>>(ab, hw2sT, P7, NN, NN, NN / 8);
    k7_epi_out<<<NN / 64, 256, 0, stream>>>(P7, deg, b2, fcW, fcb, outp + o_fg,
                                            outp + o_out);
}